// Round 8
// baseline (246.223 us; speedup 1.0000x reference)
//
#include <hip/hip_runtime.h>
#include <hip/hip_bf16.h>
#include <stdint.h>

// Problem constants (match reference)
#define NN 50000      // nodes
#define NE 800000     // edges
#define NL 100000     // label edges
#define SLOTS 64      // padded-CSR slots/node (incl. appended self-loop)
#define PADROW 50000  // dedicated all-zero row index in every h-buffer

// Bucketed CSR build (R7: direct scatter was line-bound)
#define NB 196        // dst-range buckets: bucket = dst >> 8 (256 nodes each)
#define BSH 8
#define BCAP 5376     // edges/bucket capacity; mean 4082 -> +20 sigma

typedef __attribute__((ext_vector_type(8))) short bf16x8;   // MFMA A/B frag
typedef __attribute__((ext_vector_type(4))) float f32x4;    // MFMA C/D frag
typedef __attribute__((ext_vector_type(4))) unsigned int u32x4;
typedef __attribute__((ext_vector_type(2))) unsigned int u32x2;
typedef __attribute__((ext_vector_type(8))) unsigned short u16x8;

__device__ __forceinline__ float asf(unsigned int u) {
    union { unsigned int i; float f; } c; c.i = u; return c.f;
}
__device__ __forceinline__ float bflo(unsigned int x) { return asf(x << 16); }
__device__ __forceinline__ float bfhi(unsigned int x) { return asf(x & 0xffff0000u); }
__device__ __forceinline__ unsigned short f2bf(float f) {
    union { float f; unsigned int i; } c; c.f = f;
    unsigned int u = c.i + (0x7fffu + ((c.i >> 16) & 1u));
    return (unsigned short)(u >> 16);
}

// async 16B global->LDS DMA: per-lane GLOBAL address, LDS dest = base+lane*16
__device__ __forceinline__ void dma16(const unsigned short* g, char* l) {
    __builtin_amdgcn_global_load_lds(
        (const __attribute__((address_space(1))) unsigned int*)g,
        (__attribute__((address_space(3))) unsigned int*)l, 16, 0, 0);
}

// ---- P0: W transpose+convert to bf16 Wt[n][k]; zero cursors + pad rows ----
__global__ void k_wprep(const float* __restrict__ W1, const float* __restrict__ W2,
                        const float* __restrict__ W3, unsigned short* __restrict__ Wt,
                        int* __restrict__ cursor, unsigned int* __restrict__ padA,
                        unsigned int* __restrict__ padB) {
    int idx = blockIdx.x * 256 + threadIdx.x;   // grid exactly 160
    if (idx < NB) cursor[idx] = 0;
    if (idx < 64) padA[idx] = 0;
    else if (idx < 128) padB[idx - 64] = 0;
    const float* W; unsigned short* O; int base, Mloc;
    if (idx < 16384)      { W = W1; O = Wt;         base = idx;         Mloc = 128; }
    else if (idx < 32768) { W = W2; O = Wt + 16384; base = idx - 16384; Mloc = 128; }
    else                  { W = W3; O = Wt + 32768; base = idx - 32768; Mloc = 64;  }
    int n = base >> 7, k = base & 127;
    O[base] = f2bf(W[k * Mloc + n]);
}

// ---- P1: bin edges by dst range (LDS histogram -> packed NT writes) ----
__global__ __launch_bounds__(256) void k_bin(
        const int* __restrict__ src, const int* __restrict__ dst,
        int* __restrict__ cursor, unsigned int* __restrict__ binbuf) {
    __shared__ int hcnt[NB];
    __shared__ int hbase[NB];
    __shared__ unsigned int epk[2048];
    int tid = threadIdx.x;
    if (tid < NB) hcnt[tid] = 0;
    __syncthreads();
    int e0 = blockIdx.x * 2048;                 // grid exactly 391
    int e1 = min(e0 + 2048, NE);
    for (int e = e0 + tid; e < e1; e += 256) {
        int d = dst[e], s = src[e];
        atomicAdd(&hcnt[d >> BSH], 1);
        epk[e - e0] = (unsigned int)s | ((unsigned int)d << 16);
    }
    __syncthreads();
    if (tid < NB) { hbase[tid] = atomicAdd(&cursor[tid], hcnt[tid]); hcnt[tid] = 0; }
    __syncthreads();
    for (int e = e0 + tid; e < e1; e += 256) {
        unsigned int pk = epk[e - e0];
        int b = (int)(pk >> 16) >> BSH;
        int p = hbase[b] + atomicAdd(&hcnt[b], 1);
        if (p < BCAP)
            __builtin_nontemporal_store(pk, &binbuf[(size_t)b * BCAP + p]);
    }
}

// ---- P2: per-bucket CSR build in LDS + coalesced flush ----
// Pad slots = PADROW (zero row -> mask-free gathers); self-loop appended at
// slot p=deg. Slots < 32 PERMUTED: logical p at physical 8*(p&3)+(p>>2), so
// lane-group g's physical [8g,8g+8): element k2 <-> logical 4*k2+g.
__global__ __launch_bounds__(256) void k_csr(
        const unsigned int* __restrict__ binbuf, const int* __restrict__ cursor,
        int* __restrict__ deg, unsigned short* __restrict__ colp) {
    __shared__ unsigned short lcol[256 * SLOTS];   // 32 KB
    __shared__ int ldeg[256];
    int tid = threadIdx.x;
    int blk = blockIdx.x;                          // grid exactly NB
    int base = blk << BSH;
    int nNodes = min(256, NN - base);
    ldeg[tid] = 0;
    const unsigned int fw = 0xC350C350u;           // 2x 50000
    u32x4 fill = {fw, fw, fw, fw};
    u32x4* lz = (u32x4*)lcol;
#pragma unroll
    for (int i = 0; i < 8; ++i) lz[i * 256 + tid] = fill;
    __syncthreads();
    int cnt = min(cursor[blk], BCAP);
    for (int e = tid; e < cnt; e += 256) {
        unsigned int pk = __builtin_nontemporal_load(&binbuf[(size_t)blk * BCAP + e]);
        int d = (int)(pk >> 16) - base;
        int p = atomicAdd(&ldeg[d], 1);
        if (p < SLOTS) {
            int pp = (p < 32) ? ((p & 3) * 8 + (p >> 2)) : p;
            lcol[d * SLOTS + pp] = (unsigned short)(pk & 0xffffu);
        }
    }
    __syncthreads();
    if (tid < nNodes) {
        int dv = ldeg[tid];
        deg[base + tid] = dv;
        if (dv < SLOTS) {                          // append self-loop slot
            int pp = (dv < 32) ? ((dv & 3) * 8 + (dv >> 2)) : dv;
            lcol[tid * SLOTS + pp] = (unsigned short)(base + tid);
        }
    }
    __syncthreads();
    u32x4* gout = (u32x4*)(colp + (size_t)base * SLOTS);
    const u32x4* lin = (const u32x4*)lcol;
    for (int i = tid; i < nNodes * 8; i += 256) gout[i] = lin[i];
}

// ---- layer-1 GEMM: x (fp32) -> bufA (h1). Rows >= NN untouched (pad!) ----
__global__ __launch_bounds__(256) void k_gemm1(
        const float* __restrict__ A, const unsigned short* __restrict__ Wt,
        const int* __restrict__ deg, unsigned short* __restrict__ Outb, int N) {
    constexpr int K = 128;
    constexpr int NT = 8;
    int tid = threadIdx.x;
    int lane = tid & 63, wave = tid >> 6;
    int m = lane & 15, quad = lane >> 4;
    int rowA = blockIdx.x * 64 + wave * 16 + m;    // grid exactly 782
    int rA = min(rowA, N - 1);

    bf16x8 afr[4];
    const float* p = A + (size_t)rA * K + quad * 8;
#pragma unroll
    for (int s = 0; s < 4; ++s) {
        float4 lo = *(const float4*)(p + s * 32);
        float4 hi = *(const float4*)(p + s * 32 + 4);
        bf16x8 r;
        r[0] = (short)f2bf(lo.x); r[1] = (short)f2bf(lo.y);
        r[2] = (short)f2bf(lo.z); r[3] = (short)f2bf(lo.w);
        r[4] = (short)f2bf(hi.x); r[5] = (short)f2bf(hi.y);
        r[6] = (short)f2bf(hi.z); r[7] = (short)f2bf(hi.w);
        afr[s] = r;
    }

    f32x4 acc[NT];
#pragma unroll
    for (int t = 0; t < NT; ++t) { acc[t][0] = 0.f; acc[t][1] = 0.f; acc[t][2] = 0.f; acc[t][3] = 0.f; }
#pragma unroll
    for (int t = 0; t < NT; ++t) {
        const unsigned short* wp = Wt + (size_t)(t * 16 + m) * K + quad * 8;
#pragma unroll
        for (int s = 0; s < 4; ++s) {
            bf16x8 bfr = *(const bf16x8*)(wp + s * 32);
            acc[t] = __builtin_amdgcn_mfma_f32_16x16x32_bf16(afr[s], bfr, acc[t], 0, 0, 0);
        }
    }

    int outRowBase = blockIdx.x * 64 + wave * 16 + quad * 4;
    float di[4];
#pragma unroll
    for (int i = 0; i < 4; ++i) di[i] = rsqrtf((float)deg[min(outRowBase + i, N - 1)] + 1.0f);
#pragma unroll
    for (int t = 0; t < NT; ++t)
#pragma unroll
        for (int i = 0; i < 4; ++i) {
            int rr = outRowBase + i;
            if (rr < N) Outb[(size_t)rr * 128 + t * 16 + m] = f2bf(acc[t][i] * di[i]);
        }
}

// ---- FUSED agg+gemm (R20: 5-slot DMA pipeline, 3 blocks/CU) ----
// R19 post-mortem: 53.76KB LDS -> only 2 blocks/CU resident (occ 26%).
// R20: 5 DMAs/node (logical slots 0..19; P(su<=20)=.81); tail su>20 = 3
// register loads (logical 20..31, wave-uniform branch, LLVM's counted
// waitcnt leaves the pipeline intact); su>32 ultra-rare register path.
// LDS 40KB stage + 4.25KB As = 44.3KB -> 3 blocks/CU = 12 waves (+50%).
// Steady state: 10 DMA loads in flight per wave, never drained to 0
// until the last node.
template <int M_>
__global__ __launch_bounds__(256) void k_agg_gemm(
        const unsigned short* __restrict__ hs, const int* __restrict__ deg,
        const unsigned short* __restrict__ colp, const float* __restrict__ bias,
        const unsigned short* __restrict__ Wt, unsigned short* __restrict__ Outb) {
    constexpr int K = 128;          // agg feature width and gemm K
    constexpr int NT = M_ / 64;     // col tiles per wave: 128->2, 64->1
    __shared__ __align__(16) unsigned short As[16][136];
    __shared__ __align__(16) char stage[4][2][5120];   // 20 slots x 256B x dbuf
    int tid = threadIdx.x;
    int lane = tid & 63, wave = tid >> 6;
    int tileBase = blockIdx.x * 16;
    int g = lane >> 4, c = lane & 15;
    const unsigned short* hc = hs + c * 8;
    int nodeB = tileBase + wave * 4;

    int4 dg = *(const int4*)(deg + nodeB);         // 16B aligned
    int dgv[4] = {dg.x, dg.y, dg.z, dg.w};
    u16x8 sl4[4];
#pragma unroll
    for (int t = 0; t < 4; ++t)
        sl4[t] = *(const u16x8*)(colp + (unsigned)(nodeB + t) * SLOTS + g * 8);

    // bias slice preloaded: keeps the steady-state loop VMEM-clean so the
    // counted vmcnt immediates stay exact.
    float bb[8];
    {
        const float4* bp = (const float4*)(bias + c * 8);
        float4 b0 = bp[0], b1 = bp[1];
        bb[0] = b0.x; bb[1] = b0.y; bb[2] = b0.z; bb[3] = b0.w;
        bb[4] = b1.x; bb[5] = b1.y; bb[6] = b1.z; bb[7] = b1.w;
    }

    // prologue: stage nodes 0 and 1 (5 DMAs each)
#pragma unroll
    for (int j = 0; j < 5; ++j)
        dma16(hc + (unsigned)sl4[0][j] * K, &stage[wave][0][j * 1024]);
#pragma unroll
    for (int j = 0; j < 5; ++j)
        dma16(hc + (unsigned)sl4[1][j] * K, &stage[wave][1][j * 1024]);

    // ---- agg phase: wave aggregates rows wave*4 .. wave*4+3 ----
#pragma unroll
    for (int t = 0; t < 4; ++t) {
        int node = nodeB + t;
        int su = min(dgv[t] + 1, SLOTS);           // slots incl. self

        if (t < 3) asm volatile("s_waitcnt vmcnt(5)" ::: "memory");
        else       asm volatile("s_waitcnt vmcnt(0)" ::: "memory");
        __builtin_amdgcn_sched_barrier(0);

        const char* sb = &stage[wave][t & 1][0];
        float acc[8];
#pragma unroll
        for (int k = 0; k < 8; ++k) acc[k] = 0.f;
#pragma unroll
        for (int j = 0; j < 5; ++j) {
            u32x4 v = *(const u32x4*)(sb + j * 1024 + g * 256 + c * 16);
#pragma unroll
            for (int k = 0; k < 4; ++k) {
                acc[2 * k]     += bflo(v[k]);
                acc[2 * k + 1] += bfhi(v[k]);
            }
        }

        if (su > 20) {      // tail: logical slots 20..31, register path
#pragma unroll
            for (int j = 5; j < 8; ++j) {
                u32x4 w = *(const u32x4*)(hc + (unsigned)sl4[t][j] * K);
#pragma unroll
                for (int k = 0; k < 4; ++k) {
                    acc[2 * k]     += bflo(w[k]);
                    acc[2 * k + 1] += bfhi(w[k]);
                }
            }
            if (su > 32) {  // ultra-rare: physical slots 32..63 (identity)
                u16x8 s2 = *(const u16x8*)(colp + (unsigned)node * SLOTS + 32 + g * 8);
#pragma unroll
                for (int h = 0; h < 8; ++h) {
                    u32x4 x = *(const u32x4*)(hc + (unsigned)s2[h] * K);
#pragma unroll
                    for (int k = 0; k < 4; ++k) {
                        acc[2 * k]     += bflo(x[k]);
                        acc[2 * k + 1] += bfhi(x[k]);
                    }
                }
            }
        }

        // re-issue this buffer for node t+2
        __builtin_amdgcn_sched_barrier(0);
        if (t < 2) {
#pragma unroll
            for (int j = 0; j < 5; ++j)
                dma16(hc + (unsigned)sl4[t + 2][j] * K,
                      &stage[wave][t & 1][j * 1024]);
        }

        // cross-group reduce (overlaps the just-issued DMAs)
#pragma unroll
        for (int k = 0; k < 8; ++k) {
            acc[k] += __shfl_xor(acc[k], 16, 64);
            acc[k] += __shfl_xor(acc[k], 32, 64);
        }
        if (g == 0) {
            float di = rsqrtf((float)dgv[t] + 1.0f);
            u32x4 pv;
#pragma unroll
            for (int k = 0; k < 4; ++k) {
                float o0 = fmaxf(di * acc[2 * k]     + bb[2 * k],     0.f);
                float o1 = fmaxf(di * acc[2 * k + 1] + bb[2 * k + 1], 0.f);
                pv[k] = (unsigned int)f2bf(o0) | ((unsigned int)f2bf(o1) << 16);
            }
            *(u32x4*)&As[wave * 4 + t][c * 8] = pv;   // 16B aligned
        }
    }
    __syncthreads();

    // ---- gemm phase: 16 rows x M_ cols from LDS A-tile ----
    int m = lane & 15, quad = lane >> 4;
    bf16x8 afr[4];
#pragma unroll
    for (int s = 0; s < 4; ++s)
        afr[s] = *(const bf16x8*)&As[m][s * 32 + quad * 8];

    f32x4 gacc[NT];
#pragma unroll
    for (int t = 0; t < NT; ++t) { gacc[t][0] = 0.f; gacc[t][1] = 0.f; gacc[t][2] = 0.f; gacc[t][3] = 0.f; }
#pragma unroll
    for (int t = 0; t < NT; ++t) {
        int ct = wave * NT + t;     // col tile 0..M_/16-1
        const unsigned short* wp = Wt + (size_t)(ct * 16 + m) * K + quad * 8;
#pragma unroll
        for (int s = 0; s < 4; ++s) {
            bf16x8 bfr = *(const bf16x8*)(wp + s * 32);
            gacc[t] = __builtin_amdgcn_mfma_f32_16x16x32_bf16(afr[s], bfr, gacc[t], 0, 0, 0);
        }
    }

    int rowBase = tileBase + quad * 4;
    int4 dg2 = *(const int4*)(deg + rowBase);
    int dgw[4] = {dg2.x, dg2.y, dg2.z, dg2.w};
    float di[4];
#pragma unroll
    for (int i = 0; i < 4; ++i) di[i] = rsqrtf((float)dgw[i] + 1.0f);
#pragma unroll
    for (int t = 0; t < NT; ++t) {
        int ct = wave * NT + t;
#pragma unroll
        for (int i = 0; i < 4; ++i)
            Outb[(size_t)(rowBase + i) * M_ + ct * 16 + m] = f2bf(gacc[t][i] * di[i]);
    }
}

// ---- final aggregation (F=64, no relu) -> z (bf16) ----
// R20: DMA pipeline. 128B rows -> 8 rows per dma16 (8-lane groups); 4 DMAs
// stage ALL 32 physical slots (logical 0..31, P(su<=32)=.9994 -> no mid
// branch). Double-buffered vmcnt(4) pipeline, 4 nodes/wave, grid 3125.
// LDS 32KB -> 5 blocks/CU = 20 waves. Slot indices preloaded per-lane:
// slv[t][j] = colp[node*64 + 8j + a] (colp row is L1-hot).
__global__ __launch_bounds__(256) void k_agg64(
        const unsigned short* __restrict__ hs, const int* __restrict__ deg,
        const unsigned short* __restrict__ colp, const float* __restrict__ bias,
        unsigned short* __restrict__ out, int n) {
    __shared__ __align__(16) char stage[4][2][4096];   // 32 slots x 128B x dbuf
    int tid = threadIdx.x;
    int wave = tid >> 6, lane = tid & 63;
    int a = lane >> 3, c8 = lane & 7;                  // 8 groups of 8 lanes
    int nodeB = blockIdx.x * 16 + wave * 4;            // grid exactly 3125
    const unsigned short* hc = hs + c8 * 8;            // 16B chunk per lane

    int4 dg = *(const int4*)(deg + nodeB);
    int dgv[4] = {dg.x, dg.y, dg.z, dg.w};

    // per-lane slot indices: dma j stages physical slots 8j..8j+7; this
    // lane's row for dma j is physical slot 8j + a.
    unsigned short slv[4][4];
#pragma unroll
    for (int t = 0; t < 4; ++t)
#pragma unroll
        for (int j = 0; j < 4; ++j)
            slv[t][j] = colp[(unsigned)(nodeB + t) * SLOTS + 8 * j + a];

    float bb[8];
    {
        const float4* bp = (const float4*)(bias + c8 * 8);
        float4 b0 = bp[0], b1 = bp[1];
        bb[0] = b0.x; bb[1] = b0.y; bb[2] = b0.z; bb[3] = b0.w;
        bb[4] = b1.x; bb[5] = b1.y; bb[6] = b1.z; bb[7] = b1.w;
    }

    // prologue: stage nodes 0 and 1 (4 DMAs each)
#pragma unroll
    for (int j = 0; j < 4; ++j)
        dma16(hc + (unsigned)slv[0][j] * 64, &stage[wave][0][j * 1024]);
#pragma unroll
    for (int j = 0; j < 4; ++j)
        dma16(hc + (unsigned)slv[1][j] * 64, &stage[wave][1][j * 1024]);

#pragma unroll
    for (int t = 0; t < 4; ++t) {
        int node = nodeB + t;
        int su = min(dgv[t] + 1, SLOTS);

        if (t < 3) asm volatile("s_waitcnt vmcnt(4)" ::: "memory");
        else       asm volatile("s_waitcnt vmcnt(0)" ::: "memory");
        __builtin_amdgcn_sched_barrier(0);

        const char* sb = &stage[wave][t & 1][0];
        float acc[8];
#pragma unroll
        for (int k = 0; k < 8; ++k) acc[k] = 0.f;
#pragma unroll
        for (int j = 0; j < 4; ++j) {
            // row (phys slot 8j+a) sits at sb + j*1024 + a*128
            u32x4 v = *(const u32x4*)(sb + j * 1024 + a * 128 + c8 * 16);
#pragma unroll
            for (int k = 0; k < 4; ++k) {
                acc[2 * k]     += bflo(v[k]);
                acc[2 * k + 1] += bfhi(v[k]);
            }
        }

        if (su > 32) {      // ultra-rare tail: physical slots 32..63
            if (a < 4) {    // groups 0..3 take 8 slots each
                u16x8 s2 = *(const u16x8*)(colp + (unsigned)node * SLOTS + 32 + a * 8);
#pragma unroll
                for (int h = 0; h < 8; ++h) {
                    u32x4 x = *(const u32x4*)(hc + (unsigned)s2[h] * 64);
#pragma unroll
                    for (int k = 0; k < 4; ++k) {
                        acc[2 * k]     += bflo(x[k]);
                        acc[2 * k + 1] += bfhi(x[k]);
                    }
                }
            }
        }

        __builtin_amdgcn_sched_barrier(0);
        if (t < 2) {
#pragma unroll
            for (int j = 0; j < 4; ++j)
                dma16(hc + (unsigned)slv[t + 2][j] * 64,
                      &stage[wave][t & 1][j * 1024]);
        }

        // reduce across 8 groups (bits 3,4,5 of lane)
#pragma unroll
        for (int k = 0; k < 8; ++k) {
            acc[k] += __shfl_xor(acc[k], 8, 64);
            acc[k] += __shfl_xor(acc[k], 16, 64);
            acc[k] += __shfl_xor(acc[k], 32, 64);
        }
        if (a == 0) {
            float di = rsqrtf((float)dgv[t] + 1.0f);
            u32x4 pv;
#pragma unroll
            for (int k = 0; k < 4; ++k) {
                float o0 = di * acc[2 * k]     + bb[2 * k];
                float o1 = di * acc[2 * k + 1] + bb[2 * k + 1];
                pv[k] = (unsigned int)f2bf(o0) | ((unsigned int)f2bf(o1) << 16);
            }
            *(u32x4*)(out + (size_t)node * 64 + c8 * 8) = pv;
        }
    }
}

// ---- decode: out[e] = dot(z[ls[e]], z[ld[e]]) over 64 dims, z bf16 ----
__global__ __launch_bounds__(256) void k_decode(
        const unsigned short* __restrict__ z, const int* __restrict__ ls,
        const int* __restrict__ ld, float* __restrict__ out, int nl) {
    int tid = threadIdx.x;
    int lane = tid & 63, wave = tid >> 6;
    int g = lane >> 3, c = lane & 7;
    int e = (blockIdx.x * 4 + wave) * 4 + (g >> 1);   // grid exactly 6250
    int row = (g & 1) ? ld[e] : ls[e];
    u32x4 v = *(const u32x4*)(z + (size_t)row * 64 + c * 8);
    u32x4 w;
#pragma unroll
    for (int k = 0; k < 4; ++k) w[k] = (unsigned int)__shfl_xor((int)v[k], 8, 64);
    float p = 0.f;
#pragma unroll
    for (int k = 0; k < 4; ++k)
        p += bflo(v[k]) * bflo(w[k]) + bfhi(v[k]) * bfhi(w[k]);
    p += __shfl_xor(p, 1, 64);
    p += __shfl_xor(p, 2, 64);
    p += __shfl_xor(p, 4, 64);
    if ((lane & 15) == 0) out[e] = p;   // lane in {0,16,32,48}: g even, c==0
}

// ================= launcher =================

static inline size_t align256(size_t x) { return (x + 255) & ~(size_t)255; }

extern "C" void kernel_launch(void* const* d_in, const int* in_sizes, int n_in,
                              void* d_out, int out_size, void* d_ws, size_t ws_size,
                              hipStream_t stream) {
    const float* x  = (const float*)d_in[0];
    const int*   ei = (const int*)d_in[1];    // [2][NE]: row0=src, row1=dst
    const int*   li = (const int*)d_in[2];    // [2][NL]
    const float* W1 = (const float*)d_in[3];
    const float* b1 = (const float*)d_in[4];
    const float* W2 = (const float*)d_in[5];
    const float* b2 = (const float*)d_in[6];
    const float* W3 = (const float*)d_in[7];
    const float* b3 = (const float*)d_in[8];
    float* out = (float*)d_out;

    const int* src = ei;
    const int* dst = ei + NE;
    const int* ls = li;
    const int* ld = li + NL;

    // workspace carve-up (~43 MB)
    char* ws = (char*)d_ws;
    size_t off = 0;
    int* deg    = (int*)(ws + off); off += align256(NN * 4);
    int* cursor = (int*)(ws + off); off += align256(NB * 4);
    unsigned int* binbuf = (unsigned int*)(ws + off); off += align256((size_t)NB * BCAP * 4);
    unsigned short* colp = (unsigned short*)(ws + off); off += align256((size_t)NN * SLOTS * 2);
    unsigned short* Wtb  = (unsigned short*)(ws + off); off += align256(40960 * 2);
    // bufA: h1 (128-wide, rows 0..NN-1) + pad row at 50000.
    // h3 (64-wide) = bufA upper half; its pad row 50000 aliases bufA's.
    unsigned short* bufA = (unsigned short*)(ws + off); off += align256(((size_t)NN * 128 + 128) * 2);
    unsigned short* bufB = (unsigned short*)(ws + off); off += align256(((size_t)NN * 128 + 128) * 2);
    unsigned short* bufZ = (unsigned short*)(ws + off); off += align256((size_t)NN * 64 * 2);
    unsigned short* h3 = bufA + (size_t)25000 * 128;

    // ---- CSR build + W prep (+ zero pad rows) ----
    k_wprep<<<160, 256, 0, stream>>>(W1, W2, W3, Wtb, cursor,
                                     (unsigned int*)(bufA + (size_t)PADROW * 128),
                                     (unsigned int*)(bufB + (size_t)PADROW * 128));
    k_bin<<<391, 256, 0, stream>>>(src, dst, cursor, binbuf);
    k_csr<<<NB, 256, 0, stream>>>(binbuf, cursor, deg, colp);

    // ---- layer 1 GEMM: x -> bufA (h1 = dinv * x@W1, bf16) ----
    k_gemm1<<<782, 256, 0, stream>>>(x, Wtb, deg, bufA, NN);
    // ---- fused agg1(+b1,relu) + gemm2: bufA -> bufB (h2) ----
    k_agg_gemm<128><<<3125, 256, 0, stream>>>(bufA, deg, colp, b1, Wtb + 16384, bufB);
    // ---- fused agg2(+b2,relu) + gemm3: bufB -> h3 (64-wide) ----
    k_agg_gemm<64><<<3125, 256, 0, stream>>>(bufB, deg, colp, b2, Wtb + 32768, h3);
    // ---- agg3(+b3, no relu): h3 -> bufZ (z) ----
    k_agg64<<<3125, 256, 0, stream>>>(h3, deg, colp, b3, bufZ, NN);
    // ---- decode ----
    k_decode<<<6250, 256, 0, stream>>>(bufZ, ls, ld, out, NL);
}